// Round 6
// baseline (752.659 us; speedup 1.0000x reference)
//
#include <hip/hip_runtime.h>
#include <hip/hip_bf16.h>

// LIF layer: lif_input[T,NOUT] = x[T,NIN] @ W[NOUT,NIN]^T (fp32), then sequential scan.
// fp32 GEMM on matrix pipe via fp16 2-way SCALED split, 3 MFMA products:
//   a = a0 + a1*2^-12 (a1 pre-scaled by 2^12: dodges fp16 subnormal flush)
//   C = acc0(A0B0) + 2^-12 * acc1(A0B1 + A1B0); error ~2^-24|ab| (fp32-noise level).
// Round-12 (GEMM only; splits + round-8 asm-ring scan kept):
//  - Cycle model fixed by R8/R9/R10/R11 evidence: wall/K-step/CU = 6937 cy ~
//    MFMA pipe (768 x 16x16x32 @ 4.85cy = 3725) + LDS pipe (256 ds_read_b128
//    @ ~12cy = 3072) + barriers -- SUM, not max (barrier-bursted phases defeat
//    cross-pipe overlap; R11 proved drain latency is NOT the gap).
//  - This round cuts the MFMA term only: 16x16x32 -> 32x32x16 MFMAs.
//    Measured rates (m06/m119): 32x32 = 2495 TF (8.07cy) vs 16x16 = 2075 TF
//    (4.85cy) -> MFMA term 3725 -> 3100 cy; instruction count halves.
//    LDS traffic/count IDENTICAL (32 x ds_read_b128 per wave per K-step).
//  - Product-major order (all acc0, all acc1+=a0b1, all acc1+=a1b0) separates
//    the dependent acc1 pair by 4 MFMAs; per-element accumulation order
//    unchanged (a0b1 before a1b0, k ascending) -> numerics identical.
//  - Layouts: A/B frag: row = lane&31, k = (lane>>5)*8+e (16x16 pattern
//    generalized); C/D: col=lane&31, row=(reg&3)+8*(reg>>2)+4*(lane>>5)
//    (m74/m101-verified). Swizzle: row&7 == lane&7 for all frag rows -> one
//    shared slot term per k-substep, same stage-side swizzle as R8.

#define T_STEPS 2000
#define NIN_K   8192
#define NOUT_N  4096
#define MPAD    2048

typedef __attribute__((ext_vector_type(8))) _Float16 half8;   // 8 fp16 = 4 VGPRs
typedef __attribute__((ext_vector_type(4))) float f32x4;
typedef __attribute__((ext_vector_type(16))) float f32x16;    // 32x32 acc

#define GLL16(g, l)                                                              \
    __builtin_amdgcn_global_load_lds(                                            \
        (const __attribute__((address_space(1))) void*)(g),                      \
        (__attribute__((address_space(3))) void*)(l), 16, 0, 0)

// ---------------- decompose: fp32 -> (hi, lo*2^12) fp16 ----------------
__global__ __launch_bounds__(256) void split_f32(const float* __restrict__ src,
                                                 _Float16* __restrict__ hi,
                                                 _Float16* __restrict__ lo,
                                                 size_t n_valid) {
    const size_t i8 = (size_t)(blockIdx.x * 256u + threadIdx.x) * 8;
    float vv[8];
    if (i8 < n_valid) {
        float4 v0 = *(const float4*)(src + i8);
        float4 v1 = *(const float4*)(src + i8 + 4);
        vv[0] = v0.x; vv[1] = v0.y; vv[2] = v0.z; vv[3] = v0.w;
        vv[4] = v1.x; vv[5] = v1.y; vv[6] = v1.z; vv[7] = v1.w;
    } else {
#pragma unroll
        for (int j = 0; j < 8; ++j) vv[j] = 0.f;
    }
    half8 h8, l8;
#pragma unroll
    for (int j = 0; j < 8; ++j) {
        _Float16 h = (_Float16)vv[j];               // RN
        float r = __fsub_rn(vv[j], (float)h);       // exact
        h8[j] = h;
        l8[j] = (_Float16)(r * 4096.0f);            // exact shift + one RN
    }
    *(half8*)(hi + i8) = h8;
    *(half8*)(lo + i8) = l8;
}

// ---------------- split-fp16 MFMA GEMM, BK=64, 32x32x16 MFMAs ----------------
// Block tile 128x128, 4 waves of 64x64 (2x2 frags of 32x32x16), 128 K-iters.
// LDS row layout: [row][64 halves] = 128 B/row; 16B slot s of row r holds TRUE
// k-group s^(r&7) (stage-side per-lane global-address swizzle, unchanged).
// Fragment (tile i, ks4) for lane: row = tile + (lane&31); true slot =
// ks4*2 + (lane>>5); read stored slot (true ^ (lane&7)). Bank-balanced:
// 64 lanes spread 8 slots x 8 lanes -> 1 KB over 32 banks in the 8-cy floor.
__global__ __launch_bounds__(256, 2) void gemm_f16x2(const _Float16* __restrict__ A0,
                                                     const _Float16* __restrict__ A1,
                                                     const _Float16* __restrict__ B0,
                                                     const _Float16* __restrict__ B1,
                                                     float* __restrict__ C) {
    __shared__ _Float16 lds[4][128 * 64];  // A0,A1,B0,B1: 16 KB each = 64 KB

    const int tid  = threadIdx.x;
    const int wave = tid >> 6;
    const int lane = tid & 63;
    const int bm = blockIdx.y * 128;
    const int bn = blockIdx.x * 128;
    const int wm = (wave >> 1) * 64;
    const int wn = (wave & 1) * 64;

    // Staging: per c-chunk, thread covers row c*32 + (tid>>3), 16B slot tid&7.
    // Global k-group swizzled: (tid&7) ^ ((tid>>3)&7)  [(tid>>3)&7 == row&7]
    const int srow = tid >> 3;                       // 0..31
    const int skswz = ((tid & 7) ^ (srow & 7)) * 8;  // halves

    const int hi  = lane >> 5;   // 0/1: k-half selector for 32x32 frags
    const int l31 = lane & 31;
    const int swz = lane & 7;    // == row&7 for every fragment row below

    // row*64 bases (halves) for the 2 m-subtiles / 2 n-subtiles
    int rA[2], rB[2];
#pragma unroll
    for (int i = 0; i < 2; ++i) {
        rA[i] = (wm + i * 32 + l31) * 64;
        rB[i] = (wn + i * 32 + l31) * 64;
    }

    f32x16 acc0[2][2], acc1[2][2];
#pragma unroll
    for (int i = 0; i < 2; ++i)
#pragma unroll
        for (int j = 0; j < 2; ++j) {
#pragma unroll
            for (int r = 0; r < 16; ++r) { acc0[i][j][r] = 0.f; acc1[i][j][r] = 0.f; }
        }

#pragma unroll 1
    for (int k0 = 0; k0 < NIN_K; k0 += 64) {
        __syncthreads();  // previous compute done before overwriting LDS
#pragma unroll
        for (int c = 0; c < 4; ++c) {  // 4 chunks of 32 rows
            const size_t ga = (size_t)(bm + c * 32 + srow) * NIN_K + k0 + skswz;
            const size_t gb = (size_t)(bn + c * 32 + srow) * NIN_K + k0 + skswz;
            const int base = (c * 32 + wave * 8) * 64;  // wave-uniform (HW adds lane*16B)
            GLL16(A0 + ga, &lds[0][base]);
            GLL16(A1 + ga, &lds[1][base]);
            GLL16(B0 + gb, &lds[2][base]);
            GLL16(B1 + gb, &lds[3][base]);
        }
        __syncthreads();  // staging complete

#pragma unroll
        for (int ks4 = 0; ks4 < 4; ++ks4) {  // four K=16 sub-steps
            const int slot = ((ks4 * 2 + hi) ^ swz) * 8;  // shared by all frags
            half8 a0f[2], a1f[2], b0f[2], b1f[2];
#pragma unroll
            for (int i = 0; i < 2; ++i) {
                a0f[i] = *(const half8*)&lds[0][rA[i] + slot];
                a1f[i] = *(const half8*)&lds[1][rA[i] + slot];
                b0f[i] = *(const half8*)&lds[2][rB[i] + slot];
                b1f[i] = *(const half8*)&lds[3][rB[i] + slot];
            }
            // product-major: dependent acc1 pairs separated by 4 MFMAs;
            // per-element order (a0b0 | a0b1 then a1b0) identical to R8.
#pragma unroll
            for (int i = 0; i < 2; ++i)
#pragma unroll
                for (int j = 0; j < 2; ++j)
                    acc0[i][j] = __builtin_amdgcn_mfma_f32_32x32x16_f16(a0f[i], b0f[j], acc0[i][j], 0, 0, 0);
#pragma unroll
            for (int i = 0; i < 2; ++i)
#pragma unroll
                for (int j = 0; j < 2; ++j)
                    acc1[i][j] = __builtin_amdgcn_mfma_f32_32x32x16_f16(a0f[i], b1f[j], acc1[i][j], 0, 0, 0);
#pragma unroll
            for (int i = 0; i < 2; ++i)
#pragma unroll
                for (int j = 0; j < 2; ++j)
                    acc1[i][j] = __builtin_amdgcn_mfma_f32_32x32x16_f16(a1f[i], b0f[j], acc1[i][j], 0, 0, 0);
        }
    }

    // C/D layout (m74/m101-verified): col = lane&31, row = (r&3)+8*(r>>2)+4*(lane>>5)
    const float s = 1.0f / 4096.0f;
#pragma unroll
    for (int i = 0; i < 2; ++i)
#pragma unroll
        for (int j = 0; j < 2; ++j) {
            const int mb = bm + wm + i * 32 + hi * 4;
            const int n  = bn + wn + j * 32 + l31;
#pragma unroll
            for (int r = 0; r < 16; ++r) {
                const int m = mb + (r & 3) + 8 * (r >> 2);
                C[(size_t)m * NOUT_N + n] = __fmaf_rn(acc1[i][j][r], s, acc0[i][j][r]);
            }
        }
}

// ---------------- fallback fp32 GEMM (round-1 proven; reads RAW x/w) ----------------
#define BM 64
#define BN 64
#define BK 16
#define PAD 4
__global__ __launch_bounds__(256) void gemm_bt(const float* __restrict__ A,
                                               const float* __restrict__ B,
                                               float* __restrict__ C,
                                               int M, int N, int K) {
    __shared__ float As[BK][BM + PAD];
    __shared__ float Bs[BK][BN + PAD];
    const int bm = blockIdx.y * BM, bn = blockIdx.x * BN;
    const int tid = threadIdx.x;
    const int tx = tid & 15, ty = tid >> 4;
    const int lrow = tid >> 2, lk = (tid & 3) * 4;
    float acc[4][4];
#pragma unroll
    for (int i = 0; i < 4; ++i)
#pragma unroll
        for (int j = 0; j < 4; ++j) acc[i][j] = 0.0f;
    for (int k0 = 0; k0 < K; k0 += BK) {
        const int am = bm + lrow;
        float4 av = (am < M) ? *(const float4*)(A + (size_t)am * K + k0 + lk)
                             : make_float4(0.f, 0.f, 0.f, 0.f);
        As[lk + 0][lrow] = av.x; As[lk + 1][lrow] = av.y;
        As[lk + 2][lrow] = av.z; As[lk + 3][lrow] = av.w;
        float4 bv = *(const float4*)(B + (size_t)(bn + lrow) * K + k0 + lk);
        Bs[lk + 0][lrow] = bv.x; Bs[lk + 1][lrow] = bv.y;
        Bs[lk + 2][lrow] = bv.z; Bs[lk + 3][lrow] = bv.w;
        __syncthreads();
#pragma unroll
        for (int k = 0; k < BK; ++k) {
            float a[4], b[4];
#pragma unroll
            for (int i = 0; i < 4; ++i) a[i] = As[k][ty * 4 + i];
#pragma unroll
            for (int j = 0; j < 4; ++j) b[j] = Bs[k][tx * 4 + j];
#pragma unroll
            for (int i = 0; i < 4; ++i)
#pragma unroll
                for (int j = 0; j < 4; ++j) acc[i][j] += a[i] * b[j];
        }
        __syncthreads();
    }
#pragma unroll
    for (int i = 0; i < 4; ++i) {
        const int m = bm + ty * 4 + i;
        if (m < M) {
            float* cp = C + (size_t)m * N + bn + tx * 4;
#pragma unroll
            for (int j = 0; j < 4; ++j) cp[j] = acc[i][j];
        }
    }
}

// zero-fill pad rows of lif (fallback path only; main path writes them via GEMM)
__global__ void zero_rows(float* __restrict__ p, size_t n) {
    const size_t i = (size_t)blockIdx.x * 256 + threadIdx.x;
    if (i < n) p[i] = 0.0f;
}

// ---------------- sequential LIF scan (round 8: all-asm register ring; kept) ----------------
__global__ __launch_bounds__(64) void lif_scan(const float* __restrict__ inp,
                                               const float* __restrict__ v_th_p,
                                               const float* __restrict__ v_rest_p,
                                               const float* __restrict__ v_reset_p,
                                               const float* __restrict__ t_ref_p,
                                               const float* __restrict__ tau_p,
                                               float* __restrict__ out) {
    const int lane = threadIdx.x;  // 0..63, one wave
    const int j = blockIdx.x * 64 + lane;

    const float vth = v_th_p[j], vrest = v_rest_p[j], vres = v_reset_p[j];
    const float tref = t_ref_p[j];
    const float cleak = __fmul_rn(0.001f, tau_p[j]);
    float v = vrest, refrac = 0.0f;
    out[j] = 0.0f;  // row 0 stays zero

    const float* plv = inp + (size_t)1 * NOUT_N + j;  // next row to LOAD (starts at row 1)
    float* pst = out + (size_t)1 * NOUT_N + j;        // next row to STORE (starts at t=1)

    float p00, p01, p02, p03, p04, p05, p06, p07, p08, p09, p10, p11, p12, p13, p14, p15;
    float p16, p17, p18, p19, p20, p21, p22, p23, p24, p25, p26, p27, p28, p29, p30, p31;

#define LDP(PD)                                                                   \
    asm volatile("global_load_dword %0, %1, off" : "=v"(PD) : "v"(plv) : "memory"); \
    plv += NOUT_N;

#define STEPA(PD, WSTR)                                                           \
    {                                                                             \
        asm volatile(WSTR : "+v"(PD)::"memory");                                  \
        const float in = PD;                                                      \
        const float dd = __fmul_rn(cleak, __fsub_rn(v, vrest));                   \
        v = __fsub_rn(v, dd);                                                     \
        v = (refrac == 0.0f) ? __fadd_rn(v, in) : v;                              \
        refrac = (refrac > 0.0f) ? (refrac - 0.001f) : 0.0f;                      \
        const bool s = (__fsub_rn(v, vth) >= 0.0f);                               \
        const float spk = s ? 1.0f : 0.0f;                                        \
        asm volatile("global_store_dword %0, %1, off" ::"v"(pst), "v"(spk)        \
                     : "memory");                                                 \
        pst += NOUT_N;                                                            \
        asm volatile("global_load_dword %0, %1, off" : "=v"(PD) : "v"(plv)        \
                     : "memory");                                                 \
        plv += NOUT_N;                                                            \
        refrac = s ? tref : refrac;                                               \
        v = s ? vres : v;                                                         \
    }

#define GROUP32(WSTR)                                                             \
    STEPA(p00, WSTR) STEPA(p01, WSTR) STEPA(p02, WSTR) STEPA(p03, WSTR)           \
    STEPA(p04, WSTR) STEPA(p05, WSTR) STEPA(p06, WSTR) STEPA(p07, WSTR)           \
    STEPA(p08, WSTR) STEPA(p09, WSTR) STEPA(p10, WSTR) STEPA(p11, WSTR)           \
    STEPA(p12, WSTR) STEPA(p13, WSTR) STEPA(p14, WSTR) STEPA(p15, WSTR)           \
    STEPA(p16, WSTR) STEPA(p17, WSTR) STEPA(p18, WSTR) STEPA(p19, WSTR)           \
    STEPA(p20, WSTR) STEPA(p21, WSTR) STEPA(p22, WSTR) STEPA(p23, WSTR)           \
    STEPA(p24, WSTR) STEPA(p25, WSTR) STEPA(p26, WSTR) STEPA(p27, WSTR)           \
    STEPA(p28, WSTR) STEPA(p29, WSTR) STEPA(p30, WSTR) STEPA(p31, WSTR)

#define TAILSTEP(PD)                                                              \
    {                                                                             \
        const float in = PD;                                                      \
        const float dd = __fmul_rn(cleak, __fsub_rn(v, vrest));                   \
        v = __fsub_rn(v, dd);                                                     \
        v = (refrac == 0.0f) ? __fadd_rn(v, in) : v;                              \
        refrac = (refrac > 0.0f) ? (refrac - 0.001f) : 0.0f;                      \
        const bool s = (__fsub_rn(v, vth) >= 0.0f);                               \
        *pst = s ? 1.0f : 0.0f;                                                   \
        pst += NOUT_N;                                                            \
        refrac = s ? tref : refrac;                                               \
        v = s ? vres : v;                                                         \
    }

    // prologue: rows 1..32 in flight
    LDP(p00) LDP(p01) LDP(p02) LDP(p03) LDP(p04) LDP(p05) LDP(p06) LDP(p07)
    LDP(p08) LDP(p09) LDP(p10) LDP(p11) LDP(p12) LDP(p13) LDP(p14) LDP(p15)
    LDP(p16) LDP(p17) LDP(p18) LDP(p19) LDP(p20) LDP(p21) LDP(p22) LDP(p23)
    LDP(p24) LDP(p25) LDP(p26) LDP(p27) LDP(p28) LDP(p29) LDP(p30) LDP(p31)

    // group 0: t = 1..32 (prefetch rows 33..64); younger(load row 1+d) = 31+d
    GROUP32("s_waitcnt vmcnt(31)")

    // steady: 61 groups, t = 33..1984 (prefetch up to row 2016); younger = 62
#pragma unroll 1
    for (int g = 1; g < 62; ++g) {
        GROUP32("s_waitcnt vmcnt(62)")
    }

    // drain everything (also flushes all asm stores before endpgm)
    asm volatile("s_waitcnt vmcnt(0)" ::: "memory");
    __builtin_amdgcn_sched_barrier(0);  // rule #18: no reg-use hoisting above the wait

    // tail: t = 1985..1999 from p00..p14 (loaded as rows 1985..1999)
    TAILSTEP(p00) TAILSTEP(p01) TAILSTEP(p02) TAILSTEP(p03) TAILSTEP(p04)
    TAILSTEP(p05) TAILSTEP(p06) TAILSTEP(p07) TAILSTEP(p08) TAILSTEP(p09)
    TAILSTEP(p10) TAILSTEP(p11) TAILSTEP(p12) TAILSTEP(p13) TAILSTEP(p14)

#undef LDP
#undef STEPA
#undef GROUP32
#undef TAILSTEP
}

extern "C" void kernel_launch(void* const* d_in, const int* in_sizes, int n_in,
                              void* d_out, int out_size, void* d_ws, size_t ws_size,
                              hipStream_t stream) {
    const float* x       = (const float*)d_in[0];
    const float* w       = (const float*)d_in[1];
    const float* v_th    = (const float*)d_in[2];
    const float* v_rest  = (const float*)d_in[3];
    const float* v_reset = (const float*)d_in[4];
    const float* t_ref   = (const float*)d_in[5];
    const float* tau     = (const float*)d_in[6];
    float* out = (float*)d_out;

    const size_t LIF_B = (size_t)MPAD * NOUT_N * 4;        //  32 MiB
    const size_t XS_B  = (size_t)MPAD * NIN_K * 2;         //  32 MiB each
    const size_t WS_B  = (size_t)NOUT_N * NIN_K * 2;       //  64 MiB each
    const size_t NEED  = LIF_B + 2 * XS_B + 2 * WS_B;      // 224 MiB

    char* ws = (char*)d_ws;
    float* lif = (float*)ws;

    if (ws_size >= NEED) {
        _Float16* x0 = (_Float16*)(ws + LIF_B);
        _Float16* x1 = (_Float16*)(ws + LIF_B + XS_B);
        _Float16* w0 = (_Float16*)(ws + LIF_B + 2 * XS_B);
        _Float16* w1 = (_Float16*)(ws + LIF_B + 2 * XS_B + WS_B);

        const size_t nx = (size_t)MPAD * NIN_K;
        split_f32<<<nx / 8 / 256, 256, 0, stream>>>(x, x0, x1,
                                                    (size_t)T_STEPS * NIN_K);
        const size_t nw = (size_t)NOUT_N * NIN_K;
        split_f32<<<nw / 8 / 256, 256, 0, stream>>>(w, w0, w1, nw);

        dim3 g(NOUT_N / 128, MPAD / 128);
        gemm_f16x2<<<g, 256, 0, stream>>>(x0, x1, w0, w1, lif);
    } else {
        dim3 g(NOUT_N / BN, (T_STEPS + BM - 1) / BM);
        gemm_bt<<<g, 256, 0, stream>>>(x, w, lif, T_STEPS, NOUT_N, NIN_K);
        const size_t padn = (size_t)(MPAD - T_STEPS) * NOUT_N;
        zero_rows<<<(padn + 255) / 256, 256, 0, stream>>>(lif + (size_t)T_STEPS * NOUT_N, padn);
    }

    lif_scan<<<NOUT_N / 64, 64, 0, stream>>>(lif, v_th, v_rest, v_reset, t_ref, tau, out);
}